// Round 3
// baseline (4809.534 us; speedup 1.0000x reference)
//
#include <hip/hip_runtime.h>

#define D_MODEL 768
#define NHEAD   12
#define HDIM    64
#define SEQ     1024
#define BATCH   4

typedef __attribute__((ext_vector_type(8))) short short8v;
typedef __attribute__((ext_vector_type(4))) float f32x4;

__device__ __forceinline__ ushort f2bf(float f) {
    union { float f; unsigned u; } c; c.f = f;
    unsigned r = c.u + 0x7fffu + ((c.u >> 16) & 1u);   // RNE for normal values
    return (ushort)(r >> 16);
}

// ---------------------------------------------------------------------------
// Cast fp32 -> bf16 (elementwise, 4/thread)
// ---------------------------------------------------------------------------
__global__ void cast_bf16_kernel(const float* __restrict__ src,
                                 ushort* __restrict__ dst, int n4)
{
    int idx = blockIdx.x * blockDim.x + threadIdx.x;
    if (idx >= n4) return;
    float4 v = ((const float4*)src)[idx];
    ushort4 o;
    o.x = f2bf(v.x); o.y = f2bf(v.y); o.z = f2bf(v.z); o.w = f2bf(v.w);
    ((ushort4*)dst)[idx] = o;
}

// ---------------------------------------------------------------------------
// Cast + transpose a 768x768 fp32 weight to bf16 [N][K] (so GEMM B-fragments
// read contiguous K, matching the m97 "B^T input" structure).
// ---------------------------------------------------------------------------
__global__ __launch_bounds__(256) void castT_kernel(const float* __restrict__ W,
                                                    ushort* __restrict__ WT)
{
    __shared__ float tile[32][33];
    const int kb  = blockIdx.x * 32;
    const int nb  = blockIdx.y * 32;
    const int tid = threadIdx.x;
    const int r   = tid >> 3;          // 0..31
    const int c4  = (tid & 7) * 4;     // 0,4,...,28

    float4 v = *(const float4*)(W + (size_t)(kb + r) * 768 + nb + c4);
    tile[r][c4 + 0] = v.x; tile[r][c4 + 1] = v.y;
    tile[r][c4 + 2] = v.z; tile[r][c4 + 3] = v.w;
    __syncthreads();

    ushort4 o;
    o.x = f2bf(tile[c4 + 0][r]);
    o.y = f2bf(tile[c4 + 1][r]);
    o.z = f2bf(tile[c4 + 2][r]);
    o.w = f2bf(tile[c4 + 3][r]);
    *(ushort4*)(WT + (size_t)(nb + r) * 768 + kb + c4) = o;
}

// ---------------------------------------------------------------------------
// bf16 MFMA GEMM: C[M,N] = A[M,768] @ BT[N,768]^T (+bias), fp32 out.
// 128x128 tile, BK=32, 256 threads = 4 waves (2x2), each wave 64x64 via
// 4x4 frags of mfma_f32_16x16x32_bf16. global_load_lds width-16 staging,
// linear LDS, 2-barrier loop (m97 structure).
// N may span multiple 768-wide output buffers (QKV fused: N=2304).
// ---------------------------------------------------------------------------
__global__ __launch_bounds__(256) void gemm_bf16_kernel(
    const ushort* __restrict__ A, const ushort* __restrict__ BT,
    float* __restrict__ C0, float* __restrict__ C1, float* __restrict__ C2,
    const float* __restrict__ bias)
{
    __shared__ __align__(16) ushort As[128 * 32];
    __shared__ __align__(16) ushort Bs[128 * 32];

    const int bm  = blockIdx.x * 128;
    const int bnG = blockIdx.y * 128;
    const int sel = bnG / 768;                 // 128-tile never straddles (768%128==0)
    float* C = (sel == 0) ? C0 : ((sel == 1) ? C1 : C2);
    const int ncol0 = bnG - sel * 768;

    const int tid  = threadIdx.x;
    const int lane = tid & 63;
    const int wave = tid >> 6;
    const int wm = wave >> 1, wn = wave & 1;

    f32x4 acc[4][4];
    #pragma unroll
    for (int i = 0; i < 4; i++)
        #pragma unroll
        for (int j = 0; j < 4; j++)
            acc[i][j] = (f32x4){0.f, 0.f, 0.f, 0.f};

    // staging: thread t covers LDS bytes [t*16, t*16+16) of each 4KB half
    // -> row = t/4 (64B/row), k-chunk = (t%4)*8 elems
    const int sr = tid >> 2;
    const int sk = (tid & 3) * 8;
    const ushort* Ap = A  + (size_t)(bm  + sr) * 768 + sk;
    const ushort* Bp = BT + (size_t)(bnG + sr) * 768 + sk;
    char* AsDst = (char*)As + tid * 16;
    char* BsDst = (char*)Bs + tid * 16;

    for (int k0 = 0; k0 < 768; k0 += 32) {
        __syncthreads();
        __builtin_amdgcn_global_load_lds(
            (const __attribute__((address_space(1))) void*)(Ap + k0),
            (__attribute__((address_space(3))) void*)AsDst, 16, 0, 0);
        __builtin_amdgcn_global_load_lds(
            (const __attribute__((address_space(1))) void*)(Ap + (size_t)64 * 768 + k0),
            (__attribute__((address_space(3))) void*)(AsDst + 4096), 16, 0, 0);
        __builtin_amdgcn_global_load_lds(
            (const __attribute__((address_space(1))) void*)(Bp + k0),
            (__attribute__((address_space(3))) void*)BsDst, 16, 0, 0);
        __builtin_amdgcn_global_load_lds(
            (const __attribute__((address_space(1))) void*)(Bp + (size_t)64 * 768 + k0),
            (__attribute__((address_space(3))) void*)(BsDst + 4096), 16, 0, 0);
        __syncthreads();

        short8v a[4], b[4];
        #pragma unroll
        for (int i = 0; i < 4; i++)
            a[i] = *(const short8v*)((const char*)As +
                     (wm * 64 + i * 16 + (lane & 15)) * 64 + (lane >> 4) * 16);
        #pragma unroll
        for (int j = 0; j < 4; j++)
            b[j] = *(const short8v*)((const char*)Bs +
                     (wn * 64 + j * 16 + (lane & 15)) * 64 + (lane >> 4) * 16);
        #pragma unroll
        for (int i = 0; i < 4; i++)
            #pragma unroll
            for (int j = 0; j < 4; j++)
                acc[i][j] = __builtin_amdgcn_mfma_f32_16x16x32_bf16(a[i], b[j], acc[i][j], 0, 0, 0);
    }

    // C/D layout: col = lane&15, row = (lane>>4)*4 + reg   [m89/m91-verified]
    const int cc = lane & 15, cr = lane >> 4;
    #pragma unroll
    for (int j = 0; j < 4; j++) {
        const int col = ncol0 + wn * 64 + j * 16 + cc;
        const float badd = bias ? bias[col] : 0.f;
        #pragma unroll
        for (int i = 0; i < 4; i++) {
            #pragma unroll
            for (int r = 0; r < 4; r++) {
                const int row = bm + wm * 64 + i * 16 + cr * 4 + r;
                C[(size_t)row * 768 + col] = acc[i][j][r] + badd;
            }
        }
    }
}

// ---------------------------------------------------------------------------
// Fused talking-heads attention. One block per (b, i) query row.
// (unchanged from round 1 except: av is stored as bf16, feeding the bf16
//  output GEMM directly)
// ---------------------------------------------------------------------------
__global__ __launch_bounds__(256, 1) void attn_kernel(
    const float* __restrict__ q_ws, const float* __restrict__ k_ws,
    const float* __restrict__ v_ws, const float* __restrict__ pre_attn,
    const float* __restrict__ post_attn, ushort* __restrict__ avb)
{
    __shared__ float s[NHEAD][SEQ];          // 48 KB logits -> exp -> probs
    __shared__ float q_lds[D_MODEL];         // 3 KB
    __shared__ float pre_l[NHEAD * NHEAD];
    __shared__ float wpost[NHEAD * NHEAD];
    __shared__ float l_l[NHEAD];

    const int i    = blockIdx.x;
    const int b    = blockIdx.y;
    const int tid  = threadIdx.x;
    const int lane = tid & 63;
    const int wave = tid >> 6;   // 0..3

    for (int c = tid; c < D_MODEL; c += 256)
        q_lds[c] = q_ws[((size_t)b * SEQ + i) * D_MODEL + c];
    if (tid < NHEAD * NHEAD) pre_l[tid] = pre_attn[tid];
    __syncthreads();

    // ---- scores for all heads + pre-softmax head mix (fused) ----
    for (int rep = 0; rep < 4; rep++) {
        const int j = tid + rep * 256;
        const float* krow = k_ws + ((size_t)b * SEQ + j) * D_MODEL;
        float acch[NHEAD];
        #pragma unroll
        for (int h = 0; h < NHEAD; h++) {
            float acc = 0.f;
            #pragma unroll
            for (int d = 0; d < HDIM; d += 4) {
                float4 kv = *(const float4*)(krow + h * HDIM + d);
                float4 qv = *(const float4*)(&q_lds[h * HDIM + d]);
                acc = fmaf(qv.x, kv.x, acc);
                acc = fmaf(qv.y, kv.y, acc);
                acc = fmaf(qv.z, kv.z, acc);
                acc = fmaf(qv.w, kv.w, acc);
            }
            acch[h] = acc * 0.125f;   // 1/sqrt(64)
        }
        #pragma unroll
        for (int g = 0; g < NHEAD; g++) {
            float sg = 0.f;
            #pragma unroll
            for (int h = 0; h < NHEAD; h++)
                sg = fmaf(acch[h], pre_l[h * NHEAD + g], sg);
            s[g][j] = sg;
        }
    }
    __syncthreads();

    // ---- softmax stats per head row; exp stored in place ----
    for (int h = wave; h < NHEAD; h += 4) {
        float mx = -1e30f;
        for (int jj = lane; jj < SEQ; jj += 64) mx = fmaxf(mx, s[h][jj]);
        #pragma unroll
        for (int off = 32; off > 0; off >>= 1) mx = fmaxf(mx, __shfl_xor(mx, off));
        float sum = 0.f;
        for (int jj = lane; jj < SEQ; jj += 64) {
            float e = __expf(s[h][jj] - mx);
            s[h][jj] = e;
            sum += e;
        }
        #pragma unroll
        for (int off = 32; off > 0; off >>= 1) sum += __shfl_xor(sum, off);
        if (lane == 0) l_l[h] = sum;
    }
    __syncthreads();

    if (tid < NHEAD * NHEAD) wpost[tid] = post_attn[tid] / l_l[tid / NHEAD];
    __syncthreads();

    // ---- post-softmax head mix, in place per j-column ----
    for (int rep = 0; rep < 4; rep++) {
        const int j = tid + rep * 256;
        float e[NHEAD];
        #pragma unroll
        for (int h = 0; h < NHEAD; h++) e[h] = s[h][j];
        #pragma unroll
        for (int g = 0; g < NHEAD; g++) {
            float p = 0.f;
            #pragma unroll
            for (int h = 0; h < NHEAD; h++)
                p = fmaf(e[h], wpost[h * NHEAD + g], p);
            s[g][j] = p;
        }
    }
    __syncthreads();

    // ---- PV: av[g][d] = sum_j p_g[j] * v[b, j, g*64+d] ----
    for (int rep = 0; rep < 3; rep++) {
        const int o = tid + rep * 256;       // 0..767
        const int g = o >> 6;
        const int d = o & 63;
        const float* vcol = v_ws + (size_t)b * SEQ * D_MODEL + g * HDIM + d;
        float acc = 0.f;
        for (int j = 0; j < SEQ; j += 4) {
            float4 pw = *(const float4*)&s[g][j];
            acc = fmaf(pw.x, vcol[(size_t)(j + 0) * D_MODEL], acc);
            acc = fmaf(pw.y, vcol[(size_t)(j + 1) * D_MODEL], acc);
            acc = fmaf(pw.z, vcol[(size_t)(j + 2) * D_MODEL], acc);
            acc = fmaf(pw.w, vcol[(size_t)(j + 3) * D_MODEL], acc);
        }
        // [B][H][L][HD] contiguous -> reference's flat reshape is free
        avb[(((size_t)b * NHEAD + g) * SEQ + i) * HDIM + d] = f2bf(acc);
    }
}

// ---------------------------------------------------------------------------
extern "C" void kernel_launch(void* const* d_in, const int* in_sizes, int n_in,
                              void* d_out, int out_size, void* d_ws, size_t ws_size,
                              hipStream_t stream)
{
    const float* x    = (const float*)d_in[0];
    const float* Wq   = (const float*)d_in[1];
    const float* Wk   = (const float*)d_in[2];
    const float* Wv   = (const float*)d_in[3];
    const float* pre  = (const float*)d_in[4];
    const float* post = (const float*)d_in[5];
    const float* Wo   = (const float*)d_in[6];
    const float* bo   = (const float*)d_in[7];
    float* out = (float*)d_out;

    const size_t SZ = (size_t)BATCH * SEQ * D_MODEL;   // 3,145,728
    float*  q_ws   = (float*)d_ws;
    float*  k_ws   = q_ws + SZ;
    float*  v_ws   = k_ws + SZ;
    ushort* xb_avb = (ushort*)(v_ws + SZ);  // x_bf16 during QKV GEMM, av_bf16 after
    ushort* qkvT   = xb_avb + SZ;           // [2304][768] bf16: WqT|WkT|WvT
    ushort* WoT    = qkvT + (size_t)2304 * 768;
    // total: 48.76 MB (< 50.3 MB proven in round 1)

    cast_bf16_kernel<<<(int)(SZ / 4 + 255) / 256, 256, 0, stream>>>(x, xb_avb, (int)(SZ / 4));
    castT_kernel<<<dim3(24, 24), 256, 0, stream>>>(Wq, qkvT);
    castT_kernel<<<dim3(24, 24), 256, 0, stream>>>(Wk, qkvT + (size_t)768 * 768);
    castT_kernel<<<dim3(24, 24), 256, 0, stream>>>(Wv, qkvT + (size_t)2 * 768 * 768);
    castT_kernel<<<dim3(24, 24), 256, 0, stream>>>(Wo, WoT);

    // fused QKV projection: N = 2304 -> q_ws | k_ws | v_ws
    gemm_bf16_kernel<<<dim3(32, 18), 256, 0, stream>>>(xb_avb, qkvT, q_ws, k_ws, v_ws, nullptr);

    attn_kernel<<<dim3(SEQ, BATCH), 256, 0, stream>>>(q_ws, k_ws, v_ws, pre, post, xb_avb);

    // output GEMM: av @ Wo + bo
    gemm_bf16_kernel<<<dim3(32, 6), 256, 0, stream>>>(xb_avb, WoT, out, out, out, bo);
}

// Round 7
// 355.082 us; speedup vs baseline: 13.5449x; 13.5449x over previous
//
#include <hip/hip_runtime.h>

#define D_MODEL 768
#define NHEAD   12
#define HDIM    64
#define SEQ     1024
#define BATCH   4
#define QBLK    16
#define KVBLK   32

typedef __attribute__((ext_vector_type(8))) short short8v;
typedef __attribute__((ext_vector_type(4))) float f32x4;

__device__ __forceinline__ ushort f2bf(float f) {
    union { float f; unsigned u; } c; c.f = f;
    unsigned r = c.u + 0x7fffu + ((c.u >> 16) & 1u);   // RNE for normal values
    return (ushort)(r >> 16);
}

// ---------------------------------------------------------------------------
// Cast fp32 -> bf16 (elementwise, 4/thread)
// ---------------------------------------------------------------------------
__global__ void cast_bf16_kernel(const float* __restrict__ src,
                                 ushort* __restrict__ dst, int n4)
{
    int idx = blockIdx.x * blockDim.x + threadIdx.x;
    if (idx >= n4) return;
    float4 v = ((const float4*)src)[idx];
    ushort4 o;
    o.x = f2bf(v.x); o.y = f2bf(v.y); o.z = f2bf(v.z); o.w = f2bf(v.w);
    ((ushort4*)dst)[idx] = o;
}

// ---------------------------------------------------------------------------
// Cast + transpose a 768x768 fp32 weight to bf16 [N][K]
// ---------------------------------------------------------------------------
__global__ __launch_bounds__(256) void castT_kernel(const float* __restrict__ W,
                                                    ushort* __restrict__ WT)
{
    __shared__ float tile[32][33];
    const int kb  = blockIdx.x * 32;
    const int nb  = blockIdx.y * 32;
    const int tid = threadIdx.x;
    const int r   = tid >> 3;
    const int c4  = (tid & 7) * 4;

    float4 v = *(const float4*)(W + (size_t)(kb + r) * 768 + nb + c4);
    tile[r][c4 + 0] = v.x; tile[r][c4 + 1] = v.y;
    tile[r][c4 + 2] = v.z; tile[r][c4 + 3] = v.w;
    __syncthreads();

    ushort4 o;
    o.x = f2bf(tile[c4 + 0][r]);
    o.y = f2bf(tile[c4 + 1][r]);
    o.z = f2bf(tile[c4 + 2][r]);
    o.w = f2bf(tile[c4 + 3][r]);
    *(ushort4*)(WT + (size_t)(nb + r) * 768 + kb + c4) = o;
}

// ---------------------------------------------------------------------------
// Transpose bf16 v[b][j][h*64+d] -> vt[b][h][d][j]
// ---------------------------------------------------------------------------
__global__ __launch_bounds__(256) void vT_kernel(const ushort* __restrict__ vbf,
                                                 ushort* __restrict__ vt)
{
    __shared__ ushort tile[32][33];
    const int j0 = blockIdx.x * 32;
    const int d0 = blockIdx.y * 32;
    const int bh = blockIdx.z;
    const int b  = bh / NHEAD, h = bh % NHEAD;
    const int tid = threadIdx.x;
    const int r   = tid >> 3;
    const int c4  = (tid & 7) * 4;

    ushort4 v = *(const ushort4*)(vbf + ((size_t)b * SEQ + j0 + r) * D_MODEL + h * HDIM + d0 + c4);
    tile[r][c4 + 0] = v.x; tile[r][c4 + 1] = v.y;
    tile[r][c4 + 2] = v.z; tile[r][c4 + 3] = v.w;
    __syncthreads();

    ushort4 o;
    o.x = tile[c4 + 0][r]; o.y = tile[c4 + 1][r];
    o.z = tile[c4 + 2][r]; o.w = tile[c4 + 3][r];
    *(ushort4*)(vt + ((size_t)bh * HDIM + d0 + r) * SEQ + j0 + c4) = o;
}

// ---------------------------------------------------------------------------
// bf16 MFMA GEMM (m97 structure), templated output type (fp32 or bf16).
// ---------------------------------------------------------------------------
template<int BF16OUT>
__global__ __launch_bounds__(256) void gemm_bf16_kernel(
    const ushort* __restrict__ A, const ushort* __restrict__ BT,
    void* __restrict__ C0v, void* __restrict__ C1v, void* __restrict__ C2v,
    const float* __restrict__ bias)
{
    __shared__ __align__(16) ushort As[128 * 32];
    __shared__ __align__(16) ushort Bs[128 * 32];

    const int bm  = blockIdx.x * 128;
    const int bnG = blockIdx.y * 128;
    const int sel = bnG / 768;
    void* Cv = (sel == 0) ? C0v : ((sel == 1) ? C1v : C2v);
    const int ncol0 = bnG - sel * 768;

    const int tid  = threadIdx.x;
    const int lane = tid & 63;
    const int wave = tid >> 6;
    const int wm = wave >> 1, wn = wave & 1;

    f32x4 acc[4][4];
    #pragma unroll
    for (int i = 0; i < 4; i++)
        #pragma unroll
        for (int j = 0; j < 4; j++)
            acc[i][j] = (f32x4){0.f, 0.f, 0.f, 0.f};

    const int sr = tid >> 2;
    const int sk = (tid & 3) * 8;
    const ushort* Ap = A  + (size_t)(bm  + sr) * 768 + sk;
    const ushort* Bp = BT + (size_t)(bnG + sr) * 768 + sk;
    char* AsDst = (char*)As + tid * 16;
    char* BsDst = (char*)Bs + tid * 16;

    for (int k0 = 0; k0 < 768; k0 += 32) {
        __syncthreads();
        __builtin_amdgcn_global_load_lds(
            (const __attribute__((address_space(1))) void*)(Ap + k0),
            (__attribute__((address_space(3))) void*)AsDst, 16, 0, 0);
        __builtin_amdgcn_global_load_lds(
            (const __attribute__((address_space(1))) void*)(Ap + (size_t)64 * 768 + k0),
            (__attribute__((address_space(3))) void*)(AsDst + 4096), 16, 0, 0);
        __builtin_amdgcn_global_load_lds(
            (const __attribute__((address_space(1))) void*)(Bp + k0),
            (__attribute__((address_space(3))) void*)BsDst, 16, 0, 0);
        __builtin_amdgcn_global_load_lds(
            (const __attribute__((address_space(1))) void*)(Bp + (size_t)64 * 768 + k0),
            (__attribute__((address_space(3))) void*)(BsDst + 4096), 16, 0, 0);
        __syncthreads();

        short8v a[4], b[4];
        #pragma unroll
        for (int i = 0; i < 4; i++)
            a[i] = *(const short8v*)((const char*)As +
                     (wm * 64 + i * 16 + (lane & 15)) * 64 + (lane >> 4) * 16);
        #pragma unroll
        for (int j = 0; j < 4; j++)
            b[j] = *(const short8v*)((const char*)Bs +
                     (wn * 64 + j * 16 + (lane & 15)) * 64 + (lane >> 4) * 16);
        #pragma unroll
        for (int i = 0; i < 4; i++)
            #pragma unroll
            for (int j = 0; j < 4; j++)
                acc[i][j] = __builtin_amdgcn_mfma_f32_16x16x32_bf16(a[i], b[j], acc[i][j], 0, 0, 0);
    }

    const int cc = lane & 15, cr = lane >> 4;
    #pragma unroll
    for (int j = 0; j < 4; j++) {
        const int col = ncol0 + wn * 64 + j * 16 + cc;
        const float badd = bias ? bias[col] : 0.f;
        #pragma unroll
        for (int i = 0; i < 4; i++) {
            #pragma unroll
            for (int r = 0; r < 4; r++) {
                const int row = bm + wm * 64 + i * 16 + cr * 4 + r;
                if (BF16OUT)
                    ((ushort*)Cv)[(size_t)row * 768 + col] = f2bf(acc[i][j][r] + badd);
                else
                    ((float*)Cv)[(size_t)row * 768 + col] = acc[i][j][r] + badd;
            }
        }
    }
}

// ---------------------------------------------------------------------------
// Talking-heads attention, MFMA — v3 (correct post-mix on probabilities).
// Block = (b, 16-row Q-tile); 12 waves = 1 head each.
// Phase A: per j-tile, QK^T -> stage raw S -> own-head pre-mix -> l_h += exp.
// Phase B: recompute QK^T + pre-mix + exp -> stage e -> wave g forms
//   P_g[j] = sum_h (post[h][g]/l_h) * e_h[j]   (post-mix BEFORE PV!)
// -> PV against V[g]. O written directly from accumulators.
// exp is max-free: mixed logits are bounded (|mix|<~15 -> e^15=3.3e6,
// l<=3.3e9, all comfortably in fp32 range).
// ---------------------------------------------------------------------------
__global__ __launch_bounds__(768, 1) void attn_mfma_kernel(
    const ushort* __restrict__ qb, const ushort* __restrict__ kb,
    const ushort* __restrict__ vt, const float* __restrict__ pre_attn,
    const float* __restrict__ post_attn, ushort* __restrict__ avb)
{
    __shared__ __align__(16) float s_raw[NHEAD][QBLK][36];   // 27.6 KB
    __shared__ float pre_l[NHEAD * NHEAD];
    __shared__ float post_l[NHEAD * NHEAD];
    __shared__ float l_lds[NHEAD][QBLK];

    const int i0  = blockIdx.x * QBLK;
    const int b   = blockIdx.y;
    const int tid = threadIdx.x;
    const int lane = tid & 63;
    const int h    = tid >> 6;          // wave = head (dest head g in phase B)

    if (tid < 144) pre_l[tid] = pre_attn[tid] * 0.125f;     // fold 1/sqrt(64)
    else if (tid < 288) post_l[tid - 144] = post_attn[tid - 144];

    const int lr = lane & 15;
    const int lc = lane >> 4;

    // Q frags: A[r=lr][k=lc*8+j] = Q[i0+lr][h*64 + (k | k+32)]
    const ushort* qbase = qb + ((size_t)b * SEQ + i0 + lr) * D_MODEL + h * HDIM + lc * 8;
    const short8v a_q0 = *(const short8v*)(qbase);
    const short8v a_q1 = *(const short8v*)(qbase + 32);

    const ushort* kbase  = kb + ((size_t)b * SEQ + lr) * D_MODEL + h * HDIM + lc * 8;
    const ushort* vtbase = vt + (((size_t)b * NHEAD + h) * HDIM + lr) * SEQ + lc * 8;

    // ======================= Phase A: row sums =======================
    float lsum = 0.f;
    for (int j0 = 0; j0 < SEQ; j0 += KVBLK) {
        f32x4 s_frag[2];
        #pragma unroll
        for (int cf = 0; cf < 2; cf++) {
            short8v bk0 = *(const short8v*)(kbase + (size_t)(j0 + cf * 16) * D_MODEL);
            short8v bk1 = *(const short8v*)(kbase + (size_t)(j0 + cf * 16) * D_MODEL + 32);
            f32x4 acc = (f32x4){0.f, 0.f, 0.f, 0.f};
            acc = __builtin_amdgcn_mfma_f32_16x16x32_bf16(a_q0, bk0, acc, 0, 0, 0);
            acc = __builtin_amdgcn_mfma_f32_16x16x32_bf16(a_q1, bk1, acc, 0, 0, 0);
            s_frag[cf] = acc;
        }
        __syncthreads();
        #pragma unroll
        for (int cf = 0; cf < 2; cf++)
            #pragma unroll
            for (int rr = 0; rr < 4; rr++)
                s_raw[h][lc * 4 + rr][cf * 16 + lr] = s_frag[cf][rr];
        __syncthreads();

        float mix[8];
        #pragma unroll
        for (int c = 0; c < 8; c++) mix[c] = 0.f;
        #pragma unroll
        for (int hh = 0; hh < NHEAD; hh++) {
            const float w = pre_l[hh * NHEAD + h];
            const float4 s0 = *(const float4*)(&s_raw[hh][lr][lc * 8]);
            const float4 s1 = *(const float4*)(&s_raw[hh][lr][lc * 8 + 4]);
            mix[0] = fmaf(s0.x, w, mix[0]); mix[1] = fmaf(s0.y, w, mix[1]);
            mix[2] = fmaf(s0.z, w, mix[2]); mix[3] = fmaf(s0.w, w, mix[3]);
            mix[4] = fmaf(s1.x, w, mix[4]); mix[5] = fmaf(s1.y, w, mix[5]);
            mix[6] = fmaf(s1.z, w, mix[6]); mix[7] = fmaf(s1.w, w, mix[7]);
        }
        #pragma unroll
        for (int c = 0; c < 8; c++) lsum += __expf(mix[c]);
    }
    float lrow = lsum;
    lrow += __shfl_xor(lrow, 16);
    lrow += __shfl_xor(lrow, 32);
    if (lc == 0) l_lds[h][lr] = lrow;
    __syncthreads();

    // per-lane reciprocal row sums for OWN row lr, all source heads
    float il[NHEAD];
    #pragma unroll
    for (int hh = 0; hh < NHEAD; hh++) il[hh] = 1.f / l_lds[hh][lr];

    // ======================= Phase B: P + PV =======================
    f32x4 o_acc[4];
    #pragma unroll
    for (int d = 0; d < 4; d++) o_acc[d] = (f32x4){0.f, 0.f, 0.f, 0.f};

    for (int j0 = 0; j0 < SEQ; j0 += KVBLK) {
        f32x4 s_frag[2];
        #pragma unroll
        for (int cf = 0; cf < 2; cf++) {
            short8v bk0 = *(const short8v*)(kbase + (size_t)(j0 + cf * 16) * D_MODEL);
            short8v bk1 = *(const short8v*)(kbase + (size_t)(j0 + cf * 16) * D_MODEL + 32);
            f32x4 acc = (f32x4){0.f, 0.f, 0.f, 0.f};
            acc = __builtin_amdgcn_mfma_f32_16x16x32_bf16(a_q0, bk0, acc, 0, 0, 0);
            acc = __builtin_amdgcn_mfma_f32_16x16x32_bf16(a_q1, bk1, acc, 0, 0, 0);
            s_frag[cf] = acc;
        }
        __syncthreads();   // prior tile's e-reads done
        #pragma unroll
        for (int cf = 0; cf < 2; cf++)
            #pragma unroll
            for (int rr = 0; rr < 4; rr++)
                s_raw[h][lc * 4 + rr][cf * 16 + lr] = s_frag[cf][rr];
        __syncthreads();

        // own-head pre-mix + exp (identical fp ops to phase A -> same e)
        float mix[8];
        #pragma unroll
        for (int c = 0; c < 8; c++) mix[c] = 0.f;
        #pragma unroll
        for (int hh = 0; hh < NHEAD; hh++) {
            const float w = pre_l[hh * NHEAD + h];
            const float4 s0 = *(const float4*)(&s_raw[hh][lr][lc * 8]);
            const float4 s1 = *(const float4*)(&s_raw[hh][lr][lc * 8 + 4]);
            mix[0] = fmaf(s0.x, w, mix[0]); mix[1] = fmaf(s0.y, w, mix[1]);
            mix[2] = fmaf(s0.z, w, mix[2]); mix[3] = fmaf(s0.w, w, mix[3]);
            mix[4] = fmaf(s1.x, w, mix[4]); mix[5] = fmaf(s1.y, w, mix[5]);
            mix[6] = fmaf(s1.z, w, mix[6]); mix[7] = fmaf(s1.w, w, mix[7]);
        }
        float e[8];
        #pragma unroll
        for (int c = 0; c < 8; c++) e[c] = __expf(mix[c]);

        __syncthreads();   // all waves done reading raw S
        // restage e in MIX layout: row lr, cols lc*8..+7
        #pragma unroll
        for (int c = 0; c < 8; c += 4)
            *(float4*)(&s_raw[h][lr][lc * 8 + c]) = *(float4*)(&e[c]);
        __syncthreads();

        // post-mix on probabilities: P_g[c] = sum_hh post[hh][g]/l_hh * e_hh[c]
        float pmix[8];
        #pragma unroll
        for (int c = 0; c < 8; c++) pmix[c] = 0.f;
        #pragma unroll
        for (int hh = 0; hh < NHEAD; hh++) {
            const float w = post_l[hh * NHEAD + h] * il[hh];
            const float4 e0 = *(const float4*)(&s_raw[hh][lr][lc * 8]);
            const float4 e1 = *(const float4*)(&s_raw[hh][lr][lc * 8 + 4]);
            pmix[0] = fmaf(e0.x, w, pmix[0]); pmix[1] = fmaf(e0.y, w, pmix[1]);
            pmix[2] = fmaf(e0.z, w, pmix[2]); pmix[3] = fmaf(e0.w, w, pmix[3]);
            pmix[4] = fmaf(e1.x, w, pmix[4]); pmix[5] = fmaf(e1.y, w, pmix[5]);
            pmix[6] = fmaf(e1.z, w, pmix[6]); pmix[7] = fmaf(e1.w, w, pmix[7]);
        }
        short8v pa;
        #pragma unroll
        for (int c = 0; c < 8; c++) ((ushort*)&pa)[c] = f2bf(pmix[c]);

        // PV: O_g[16][64] += P_g[16][32] @ V_g[32][64]
        #pragma unroll
        for (int d = 0; d < 4; d++) {
            short8v bv = *(const short8v*)(vtbase + (size_t)(d * 16) * SEQ + j0);
            o_acc[d] = __builtin_amdgcn_mfma_f32_16x16x32_bf16(pa, bv, o_acc[d], 0, 0, 0);
        }
    }

    // ---- store O directly (row = lc*4+rr, col = d*16+lr) ----
    #pragma unroll
    for (int d = 0; d < 4; d++)
        #pragma unroll
        for (int rr = 0; rr < 4; rr++)
            avb[(((size_t)b * NHEAD + h) * SEQ + i0 + lc * 4 + rr) * HDIM + d * 16 + lr]
                = f2bf(o_acc[d][rr]);
}

// ---------------------------------------------------------------------------
extern "C" void kernel_launch(void* const* d_in, const int* in_sizes, int n_in,
                              void* d_out, int out_size, void* d_ws, size_t ws_size,
                              hipStream_t stream)
{
    const float* x    = (const float*)d_in[0];
    const float* Wq   = (const float*)d_in[1];
    const float* Wk   = (const float*)d_in[2];
    const float* Wv   = (const float*)d_in[3];
    const float* pre  = (const float*)d_in[4];
    const float* post = (const float*)d_in[5];
    const float* Wo   = (const float*)d_in[6];
    const float* bo   = (const float*)d_in[7];
    float* out = (float*)d_out;

    const size_t SZ = (size_t)BATCH * SEQ * D_MODEL;   // 3,145,728
    ushort* qbf    = (ushort*)d_ws;
    ushort* kbf    = qbf + SZ;
    ushort* vbf    = kbf + SZ;
    ushort* vt     = vbf + SZ;
    ushort* xb_avb = vt  + SZ;              // x_bf16 for QKV GEMM, av_bf16 after
    ushort* qkvT   = xb_avb + SZ;           // [2304][768]: WqT|WkT|WvT
    ushort* WoT    = qkvT + (size_t)2304 * 768;
    // total 36.2 MB (< 48.76 MB proven in round 3)

    cast_bf16_kernel<<<(int)(SZ / 4 + 255) / 256, 256, 0, stream>>>(x, xb_avb, (int)(SZ / 4));
    castT_kernel<<<dim3(24, 24), 256, 0, stream>>>(Wq, qkvT);
    castT_kernel<<<dim3(24, 24), 256, 0, stream>>>(Wk, qkvT + (size_t)768 * 768);
    castT_kernel<<<dim3(24, 24), 256, 0, stream>>>(Wv, qkvT + (size_t)2 * 768 * 768);
    castT_kernel<<<dim3(24, 24), 256, 0, stream>>>(Wo, WoT);

    gemm_bf16_kernel<1><<<dim3(32, 18), 256, 0, stream>>>(xb_avb, qkvT, qbf, kbf, vbf, nullptr);

    vT_kernel<<<dim3(32, 2, BATCH * NHEAD), 256, 0, stream>>>(vbf, vt);

    attn_mfma_kernel<<<dim3(SEQ / QBLK, BATCH), 768, 0, stream>>>(qbf, kbf, vt, pre, post, xb_avb);

    gemm_bf16_kernel<0><<<dim3(32, 6), 256, 0, stream>>>(qbf == nullptr ? nullptr : xb_avb, WoT, out, out, out, bo);
}